// Round 6
// baseline (604.681 us; speedup 1.0000x reference)
//
#include <hip/hip_runtime.h>
#include <math.h>

typedef __bf16 bf16_t;
typedef __bf16 bf16x8 __attribute__((ext_vector_type(8)));
typedef __bf16 bf16x4 __attribute__((ext_vector_type(4)));
typedef float f32x4 __attribute__((ext_vector_type(4)));

#define N_TOK 4096
#define DMODEL 1024
#define FFN 1024
#define NEXP 8
#define HIST_BLK 16

#define BM 128
#define BN 128
#define BK 32
#define LDK 40  // padded LDS k-stride: 16B-aligned, benign 2-way bank aliasing

// ---------------- prep: all weight transposes fp32->bf16, 16B/lane stores ----------------
__global__ void transpose_all_kernel(const float* __restrict__ w1, const float* __restrict__ w2,
                                     const float* __restrict__ sgu, const float* __restrict__ sdw,
                                     bf16_t* __restrict__ w1t, bf16_t* __restrict__ w2t,
                                     bf16_t* __restrict__ sgut, bf16_t* __restrict__ sdt) {
  __shared__ float tile[64 * 66];
  const int z = blockIdx.z;
  const float* in;
  bf16_t* out;
  int C = 1024;
  bool remap = false;
  if (z < 8) {
    in = w1 + (size_t)z * 1048576; out = w1t + (size_t)z * 1048576;
  } else if (z < 16) {
    in = w2 + (size_t)(z - 8) * 1048576; out = w2t + (size_t)(z - 8) * 1048576;
  } else if (z == 16) {
    in = sgu; out = sgut; C = 2048; remap = true;
  } else {
    in = sdw; out = sdt;
  }
  const int c0 = blockIdx.x * 64, r0 = blockIdx.y * 64;
  if (c0 >= C) return;
  const int tid = threadIdx.x;
  const int row = tid >> 2;
  const int ch = (tid & 3) * 16;
  const float* src = in + (size_t)(r0 + row) * C + c0 + ch;
  float* trow = &tile[row * 66 + ch];
#pragma unroll
  for (int q = 0; q < 4; q++) {
    float4 v = *reinterpret_cast<const float4*>(src + 4 * q);
    *reinterpret_cast<float2*>(trow + 4 * q) = make_float2(v.x, v.y);
    *reinterpret_cast<float2*>(trow + 4 * q + 2) = make_float2(v.z, v.w);
  }
  __syncthreads();
  const int c = tid >> 2;
  const int cg = c0 + c;
  const int oc = remap ? ((cg < FFN) ? 2 * cg : 2 * (cg - FFN) + 1) : cg;
#pragma unroll
  for (int p = 0; p < 2; p++) {
    const int rb = (tid & 3) + 4 * p;
    bf16x8 o;
#pragma unroll
    for (int j = 0; j < 8; j++) o[j] = (bf16_t)tile[(rb * 8 + j) * 66 + c];
    *reinterpret_cast<bf16x8*>(out + (size_t)oc * 1024 + r0 + rb * 8) = o;
  }
}

// ---------------- router: logits/softmax/top2/sigmoid gate + fused x->bf16 cast ----------------
__global__ void router_kernel(const float* __restrict__ x, const float* __restrict__ rw,
                              const float* __restrict__ gw, bf16_t* __restrict__ xb,
                              int* __restrict__ topi, float* __restrict__ topw,
                              float* __restrict__ sig) {
  const int t = blockIdx.x;
  const int lane = threadIdx.x;  // 64
  const float* xr = x + (size_t)t * DMODEL;
  bf16_t* xbr = xb + (size_t)t * DMODEL;
  float acc[NEXP] = {0.f, 0.f, 0.f, 0.f, 0.f, 0.f, 0.f, 0.f};
  float accg = 0.f;
#pragma unroll
  for (int i = 0; i < 4; i++) {
    const int d = i * 256 + lane * 4;
    float4 xv = *reinterpret_cast<const float4*>(xr + d);
    bf16x4 o;
    o[0] = (bf16_t)xv.x; o[1] = (bf16_t)xv.y; o[2] = (bf16_t)xv.z; o[3] = (bf16_t)xv.w;
    *reinterpret_cast<bf16x4*>(xbr + d) = o;
    const float xs[4] = {xv.x, xv.y, xv.z, xv.w};
#pragma unroll
    for (int j = 0; j < 4; j++) {
      const float4* r = reinterpret_cast<const float4*>(rw + (size_t)(d + j) * NEXP);
      float4 r0 = r[0], r1 = r[1];
      float xj = xs[j];
      acc[0] += xj * r0.x; acc[1] += xj * r0.y; acc[2] += xj * r0.z; acc[3] += xj * r0.w;
      acc[4] += xj * r1.x; acc[5] += xj * r1.y; acc[6] += xj * r1.z; acc[7] += xj * r1.w;
      accg += xj * gw[d + j];
    }
  }
#pragma unroll
  for (int e = 0; e < NEXP; e++)
    for (int s = 32; s > 0; s >>= 1) acc[e] += __shfl_down(acc[e], s, 64);
  for (int s = 32; s > 0; s >>= 1) accg += __shfl_down(accg, s, 64);
  if (lane == 0) {
    float mx = acc[0];
#pragma unroll
    for (int e = 1; e < NEXP; e++) mx = fmaxf(mx, acc[e]);
    float p[NEXP], sum = 0.f;
#pragma unroll
    for (int e = 0; e < NEXP; e++) { p[e] = __expf(acc[e] - mx); sum += p[e]; }
    int i1 = 0;
#pragma unroll
    for (int e = 1; e < NEXP; e++) if (acc[e] > acc[i1]) i1 = e;
    int i2 = (i1 == 0) ? 1 : 0;
#pragma unroll
    for (int e = 0; e < NEXP; e++) if (e != i1 && acc[e] > acc[i2]) i2 = e;
    float inv = 1.f / sum;
    topi[2 * t] = i1;     topw[2 * t] = p[i1] * inv;
    topi[2 * t + 1] = i2; topw[2 * t + 1] = p[i2] * inv;
    sig[t] = 1.f / (1.f + __expf(-accg));
  }
}

// ---------------- per-block expert histogram (LDS only) ----------------
__global__ void hist_kernel(const int* __restrict__ topi, int* __restrict__ block_counts) {
  __shared__ int h[NEXP];
  const int tid = threadIdx.x;
  if (tid < NEXP) h[tid] = 0;
  __syncthreads();
  const int t = blockIdx.x * 256 + tid;
  atomicAdd(&h[topi[2 * t]], 1);
  atomicAdd(&h[topi[2 * t + 1]], 1);
  __syncthreads();
  if (tid < NEXP) block_counts[blockIdx.x * NEXP + tid] = h[tid];
}

// ---------------- gather (scan fused: each block redundantly prefixes block_counts) ----------------
__global__ void gather_kernel(const int* __restrict__ topi, const float* __restrict__ topw,
                              const int* __restrict__ block_counts, int* __restrict__ slot_tok,
                              float* __restrict__ slot_w, int* __restrict__ slot_of,
                              int* __restrict__ offsets, int* __restrict__ counts) {
  __shared__ int cur[NEXP];
  const int tid = threadIdx.x;
  if (tid < NEXP) {
    int off = 0;
    for (int f = 0; f < tid; f++)
      for (int b = 0; b < HIST_BLK; b++) off += block_counts[b * NEXP + f];
    int bb = off;
    for (int b = 0; b < (int)blockIdx.x; b++) bb += block_counts[b * NEXP + tid];
    cur[tid] = bb;
    if (blockIdx.x == 0) {
      offsets[tid] = off;
      int tot = 0;
      for (int b = 0; b < HIST_BLK; b++) tot += block_counts[b * NEXP + tid];
      counts[tid] = tot;
    }
  }
  __syncthreads();
  const int t = blockIdx.x * 256 + tid;
#pragma unroll
  for (int j = 0; j < 2; j++) {
    int e = topi[2 * t + j];
    int s = atomicAdd(&cur[e], 1);
    slot_tok[s] = t;
    slot_w[s] = topw[2 * t + j];
    slot_of[2 * t + j] = s;
  }
}

// ---------------- combine: out[t] += Y[slot0] + Y[slot1] ----------------
__global__ void combine_kernel(const bf16_t* __restrict__ Y, const int* __restrict__ slot_of,
                               float* __restrict__ out) {
  int i = blockIdx.x * blockDim.x + threadIdx.x;
  int t = i >> 7;
  int d = (i & 127) << 3;
  int s0 = slot_of[2 * t], s1 = slot_of[2 * t + 1];
  bf16x8 a = *reinterpret_cast<const bf16x8*>(Y + (size_t)s0 * DMODEL + d);
  bf16x8 b = *reinterpret_cast<const bf16x8*>(Y + (size_t)s1 * DMODEL + d);
  float* o = out + (size_t)t * DMODEL + d;
  float4 o0 = *reinterpret_cast<float4*>(o);
  float4 o1 = *reinterpret_cast<float4*>(o + 4);
  o0.x += (float)a[0] + (float)b[0]; o0.y += (float)a[1] + (float)b[1];
  o0.z += (float)a[2] + (float)b[2]; o0.w += (float)a[3] + (float)b[3];
  o1.x += (float)a[4] + (float)b[4]; o1.y += (float)a[5] + (float)b[5];
  o1.z += (float)a[6] + (float)b[6]; o1.w += (float)a[7] + (float)b[7];
  *reinterpret_cast<float4*>(o) = o0;
  *reinterpret_cast<float4*>(o + 4) = o1;
}

// ---------------- merged MFMA GEMM, 128x128 tile, BK=32, LDS ping-pong (1 barrier/iter) -------
// PHASE 0 (up):   z==0: S = silu_pair(xb @ sgut interleaved)   z>0: H[slot]=silu(xb[tok] @ w1t[e])
// PHASE 1 (down): z==0: out = sig * (S @ sdt)                  z>0: Y[slot]=w * (H[slot] @ w2t[e])
template <int PHASE>
__global__ __launch_bounds__(256) void moe_gemm_kernel(
    const bf16_t* __restrict__ A0, const bf16_t* __restrict__ B0,
    const bf16_t* __restrict__ A1, const bf16_t* __restrict__ B1,
    void* __restrict__ C0, void* __restrict__ C1,
    const int* __restrict__ offsets, const int* __restrict__ counts,
    const int* __restrict__ slot_tok, const float* __restrict__ slot_w,
    const float* __restrict__ sig) {
  __shared__ bf16_t lds_a[2][BM * LDK];  // ping-pong: 2 x 10 KB
  __shared__ bf16_t lds_b[2][BN * LDK];  // total 40 KB -> 4 blocks/CU

  const int z = blockIdx.z;
  int m0, mEnd;
  const bf16_t *Ap, *Bp;
  if (z == 0) {
    m0 = blockIdx.y * BM;
    mEnd = N_TOK;
    Ap = A0; Bp = B0;
  } else {
    if (PHASE == 0 && blockIdx.x >= FFN / BN) return;  // up-phase grid.x=16, experts use 8
    const int e = z - 1;
    m0 = offsets[e] + (int)blockIdx.y * BM;
    mEnd = offsets[e] + counts[e];
    if (m0 >= mEnd) return;
    Ap = A1; Bp = B1 + (size_t)e * FFN * DMODEL;
  }
  const int n0 = blockIdx.x * BN;

  const int tid = threadIdx.x;
  const int lane = tid & 63;
  const int wave = tid >> 6;
  const int qd = lane >> 4;
  const int lm = lane & 15;
  const int wm = (wave >> 1) * 64;
  const int wn = (wave & 1) * 64;

  // staging: thread handles rows arow, arow+64 (per tile side), 16B chunk cc
  const int arow = tid >> 2;
  const int cc = tid & 3;
  const bf16_t* pa[2];
  const bf16_t* pb[2];
#pragma unroll
  for (int h = 0; h < 2; h++) {
    int s = m0 + arow + h * 64;
    int g;
    if (z == 0) g = s;
    else if (PHASE == 0) g = slot_tok[(s < mEnd) ? s : (mEnd - 1)];
    else g = (s < mEnd) ? s : (mEnd - 1);
    pa[h] = Ap + (size_t)g * 1024 + cc * 8;  // K = 1024 both phases
    pb[h] = Bp + (size_t)(n0 + arow + h * 64) * 1024 + cc * 8;
  }

  f32x4 acc[4][4] = {};
  uint4 ra[2], rb[2];

  // prologue: tile 0 -> regs -> buf 0
#pragma unroll
  for (int h = 0; h < 2; h++) {
    ra[h] = *reinterpret_cast<const uint4*>(pa[h]);
    rb[h] = *reinterpret_cast<const uint4*>(pb[h]);
  }
#pragma unroll
  for (int h = 0; h < 2; h++) {
    *reinterpret_cast<uint4*>(&lds_a[0][(arow + h * 64) * LDK + cc * 8]) = ra[h];
    *reinterpret_cast<uint4*>(&lds_b[0][(arow + h * 64) * LDK + cc * 8]) = rb[h];
  }
  __syncthreads();

  int cur = 0;
  for (int k0 = 0; k0 < 1024; k0 += BK) {
    const bool more = (k0 + BK) < 1024;
    // issue next tile's global loads BEFORE the MFMA block: latency hidden behind MFMA
    if (more) {
#pragma unroll
      for (int h = 0; h < 2; h++) {
        ra[h] = *reinterpret_cast<const uint4*>(pa[h] + k0 + BK);
        rb[h] = *reinterpret_cast<const uint4*>(pb[h] + k0 + BK);
      }
    }
    bf16x8 af[4], bfr[4];
#pragma unroll
    for (int i = 0; i < 4; i++)
      af[i] = *reinterpret_cast<const bf16x8*>(&lds_a[cur][(wm + i * 16 + lm) * LDK + qd * 8]);
#pragma unroll
    for (int j = 0; j < 4; j++)
      bfr[j] = *reinterpret_cast<const bf16x8*>(&lds_b[cur][(wn + j * 16 + lm) * LDK + qd * 8]);
#pragma unroll
    for (int i = 0; i < 4; i++)
#pragma unroll
      for (int j = 0; j < 4; j++)
        acc[i][j] = __builtin_amdgcn_mfma_f32_16x16x32_bf16(af[i], bfr[j], acc[i][j], 0, 0, 0);
    // store next tile into the other buffer (read by nobody this iter), single barrier
    if (more) {
      const int nxt = cur ^ 1;
#pragma unroll
      for (int h = 0; h < 2; h++) {
        *reinterpret_cast<uint4*>(&lds_a[nxt][(arow + h * 64) * LDK + cc * 8]) = ra[h];
        *reinterpret_cast<uint4*>(&lds_b[nxt][(arow + h * 64) * LDK + cc * 8]) = rb[h];
      }
    }
    cur ^= 1;
    __syncthreads();
  }

  // epilogue: C row = (lane>>4)*4 + reg, col = lane&15  [HW-verified]
#pragma unroll
  for (int i = 0; i < 4; i++) {
#pragma unroll
    for (int r = 0; r < 4; r++) {
      const int gm = m0 + wm + i * 16 + qd * 4 + r;
      const bool mOk = (z == 0) || (gm < mEnd);
#pragma unroll
      for (int j = 0; j < 4; j++) {
        const int col = n0 + wn + j * 16 + lm;
        float v = acc[i][j][r];
        if (PHASE == 0) {
          if (z == 0) {
            // cols interleaved: even = gate f, odd = up f (f = col>>1); pair via shfl_xor
            float u = __shfl_xor(v, 1, 64);
            if ((lane & 1) == 0) {
              float sv = v / (1.f + __expf(-v)) * u;
              ((bf16_t*)C0)[(size_t)gm * FFN + (col >> 1)] = (bf16_t)sv;
            }
          } else if (mOk) {
            ((bf16_t*)C1)[(size_t)gm * FFN + col] = (bf16_t)(v / (1.f + __expf(-v)));
          }
        } else {
          if (z == 0) {
            ((float*)C0)[(size_t)gm * DMODEL + col] = sig[gm] * v;
          } else if (mOk) {
            ((bf16_t*)C1)[(size_t)gm * DMODEL + col] = (bf16_t)(slot_w[gm] * v);
          }
        }
      }
    }
  }
}

extern "C" void kernel_launch(void* const* d_in, const int* in_sizes, int n_in, void* d_out,
                              int out_size, void* d_ws, size_t ws_size, hipStream_t stream) {
  const float* x = (const float*)d_in[0];
  const float* rw = (const float*)d_in[1];
  const float* w1 = (const float*)d_in[2];
  const float* w2 = (const float*)d_in[3];
  const float* sgu = (const float*)d_in[4];
  const float* sdw = (const float*)d_in[5];
  const float* gw = (const float*)d_in[6];
  float* out = (float*)d_out;

  char* ws = (char*)d_ws;
  size_t off = 0;
  auto alloc = [&](size_t bytes) -> void* {
    void* p = ws + off;
    off += (bytes + 255) & ~(size_t)255;
    return p;
  };
  bf16_t* xb = (bf16_t*)alloc((size_t)N_TOK * DMODEL * 2);
  bf16_t* w1t = (bf16_t*)alloc((size_t)NEXP * DMODEL * FFN * 2);
  bf16_t* w2t = (bf16_t*)alloc((size_t)NEXP * DMODEL * FFN * 2);
  bf16_t* sgut = (bf16_t*)alloc((size_t)2 * FFN * DMODEL * 2);  // rows gate/up interleaved
  bf16_t* sdt = (bf16_t*)alloc((size_t)DMODEL * FFN * 2);
  bf16_t* S = (bf16_t*)alloc((size_t)N_TOK * FFN * 2);
  bf16_t* H = (bf16_t*)alloc((size_t)N_TOK * 2 * FFN * 2);    // slot-major
  bf16_t* Y = (bf16_t*)alloc((size_t)N_TOK * 2 * DMODEL * 2); // slot-major
  int* topi = (int*)alloc(N_TOK * 2 * 4);
  float* topw = (float*)alloc(N_TOK * 2 * 4);
  float* sig = (float*)alloc(N_TOK * 4);
  int* slot_tok = (int*)alloc(N_TOK * 2 * 4);
  float* slot_w = (float*)alloc(N_TOK * 2 * 4);
  int* slot_of = (int*)alloc(N_TOK * 2 * 4);
  int* block_counts = (int*)alloc(HIST_BLK * NEXP * 4);
  int* counts = (int*)alloc(NEXP * 4);
  int* offsets = (int*)alloc(NEXP * 4);

  // prep + routing
  transpose_all_kernel<<<dim3(32, 16, 18), 256, 0, stream>>>(w1, w2, sgu, sdw, w1t, w2t, sgut,
                                                             sdt);
  router_kernel<<<N_TOK, 64, 0, stream>>>(x, rw, gw, xb, topi, topw, sig);
  hist_kernel<<<HIST_BLK, 256, 0, stream>>>(topi, block_counts);
  gather_kernel<<<HIST_BLK, 256, 0, stream>>>(topi, topw, block_counts, slot_tok, slot_w,
                                              slot_of, offsets, counts);

  // up-phase: shared gate_up (z=0, silu fused) + 8 expert W1 GEMMs, one launch
  moe_gemm_kernel<0><<<dim3(2 * FFN / BN, N_TOK / BM, 1 + NEXP), 256, 0, stream>>>(
      xb, sgut, xb, w1t, S, H, offsets, counts, slot_tok, slot_w, sig);
  // down-phase: shared down (z=0, sig-scaled f32, initializes out) + 8 expert W2 GEMMs
  moe_gemm_kernel<1><<<dim3(DMODEL / BN, N_TOK / BM, 1 + NEXP), 256, 0, stream>>>(
      S, sdt, H, w2t, out, Y, offsets, counts, slot_tok, slot_w, sig);
  // routed combine
  combine_kernel<<<N_TOK * DMODEL / 8 / 256, 256, 0, stream>>>(Y, slot_of, out);
}

// Round 7
// 310.519 us; speedup vs baseline: 1.9473x; 1.9473x over previous
//
#include <hip/hip_runtime.h>
#include <math.h>

typedef __bf16 bf16_t;
typedef __bf16 bf16x8 __attribute__((ext_vector_type(8)));
typedef __bf16 bf16x4 __attribute__((ext_vector_type(4)));
typedef float f32x4 __attribute__((ext_vector_type(4)));

#define N_TOK 4096
#define DMODEL 1024
#define FFN 1024
#define NEXP 8
#define HIST_BLK 16

#define BM 128
#define BN 128
#define BK 32
#define LDK 40  // padded LDS k-stride (R2-proven): 16B-aligned, benign bank aliasing

// ---------------- prep: all weight transposes fp32->bf16 in ONE launch (R3-proven) ----------------
// z<8: w1[e] (D,F)->(F,D); z<16: w2[e-8] (F,D)->(D,F); z==16: sgu (D,2F)->(2F,D) with gate/up
// row-interleave (row 2f = gate f, row 2f+1 = up f); z==17: sdw (F,D)->(D,F)
__global__ void transpose_all_kernel(const float* __restrict__ w1, const float* __restrict__ w2,
                                     const float* __restrict__ sgu, const float* __restrict__ sdw,
                                     bf16_t* __restrict__ w1t, bf16_t* __restrict__ w2t,
                                     bf16_t* __restrict__ sgut, bf16_t* __restrict__ sdt) {
  __shared__ float tile[32][33];
  const int z = blockIdx.z;
  const float* in;
  bf16_t* out;
  int C = 1024;
  bool remap = false;
  if (z < 8) {
    in = w1 + (size_t)z * 1048576; out = w1t + (size_t)z * 1048576;
  } else if (z < 16) {
    in = w2 + (size_t)(z - 8) * 1048576; out = w2t + (size_t)(z - 8) * 1048576;
  } else if (z == 16) {
    in = sgu; out = sgut; C = 2048; remap = true;
  } else {
    in = sdw; out = sdt;
  }
  const int R = 1024;
  const int c0 = blockIdx.x * 32, r0 = blockIdx.y * 32;
  if (c0 >= C) return;
  const int tx = threadIdx.x, ty = threadIdx.y;
#pragma unroll
  for (int i = 0; i < 32; i += 8)
    tile[ty + i][tx] = in[(size_t)(r0 + ty + i) * C + (c0 + tx)];
  __syncthreads();
#pragma unroll
  for (int i = 0; i < 32; i += 8) {
    int c = c0 + ty + i;
    int oc = remap ? ((c < FFN) ? 2 * c : 2 * (c - FFN) + 1) : c;
    out[(size_t)oc * R + (r0 + tx)] = (bf16_t)tile[tx][ty + i];
  }
}

// ---------------- router: logits/softmax/top2/sigmoid gate + fused x->bf16 cast ----------------
__global__ void router_kernel(const float* __restrict__ x, const float* __restrict__ rw,
                              const float* __restrict__ gw, bf16_t* __restrict__ xb,
                              int* __restrict__ topi, float* __restrict__ topw,
                              float* __restrict__ sig) {
  const int t = blockIdx.x;
  const int lane = threadIdx.x;  // 64
  const float* xr = x + (size_t)t * DMODEL;
  bf16_t* xbr = xb + (size_t)t * DMODEL;
  float acc[NEXP] = {0.f, 0.f, 0.f, 0.f, 0.f, 0.f, 0.f, 0.f};
  float accg = 0.f;
#pragma unroll
  for (int i = 0; i < 4; i++) {
    const int d = i * 256 + lane * 4;
    float4 xv = *reinterpret_cast<const float4*>(xr + d);
    bf16x4 o;
    o[0] = (bf16_t)xv.x; o[1] = (bf16_t)xv.y; o[2] = (bf16_t)xv.z; o[3] = (bf16_t)xv.w;
    *reinterpret_cast<bf16x4*>(xbr + d) = o;
    const float xs[4] = {xv.x, xv.y, xv.z, xv.w};
#pragma unroll
    for (int j = 0; j < 4; j++) {
      const float4* r = reinterpret_cast<const float4*>(rw + (size_t)(d + j) * NEXP);
      float4 r0 = r[0], r1 = r[1];
      float xj = xs[j];
      acc[0] += xj * r0.x; acc[1] += xj * r0.y; acc[2] += xj * r0.z; acc[3] += xj * r0.w;
      acc[4] += xj * r1.x; acc[5] += xj * r1.y; acc[6] += xj * r1.z; acc[7] += xj * r1.w;
      accg += xj * gw[d + j];
    }
  }
#pragma unroll
  for (int e = 0; e < NEXP; e++)
    for (int s = 32; s > 0; s >>= 1) acc[e] += __shfl_down(acc[e], s, 64);
  for (int s = 32; s > 0; s >>= 1) accg += __shfl_down(accg, s, 64);
  if (lane == 0) {
    float mx = acc[0];
#pragma unroll
    for (int e = 1; e < NEXP; e++) mx = fmaxf(mx, acc[e]);
    float p[NEXP], sum = 0.f;
#pragma unroll
    for (int e = 0; e < NEXP; e++) { p[e] = __expf(acc[e] - mx); sum += p[e]; }
    int i1 = 0;
#pragma unroll
    for (int e = 1; e < NEXP; e++) if (acc[e] > acc[i1]) i1 = e;
    int i2 = (i1 == 0) ? 1 : 0;
#pragma unroll
    for (int e = 0; e < NEXP; e++) if (e != i1 && acc[e] > acc[i2]) i2 = e;
    float inv = 1.f / sum;
    topi[2 * t] = i1;     topw[2 * t] = p[i1] * inv;
    topi[2 * t + 1] = i2; topw[2 * t + 1] = p[i2] * inv;
    sig[t] = 1.f / (1.f + __expf(-accg));
  }
}

// ---------------- per-block expert histogram (LDS only) ----------------
__global__ void hist_kernel(const int* __restrict__ topi, int* __restrict__ block_counts) {
  __shared__ int h[NEXP];
  const int tid = threadIdx.x;
  if (tid < NEXP) h[tid] = 0;
  __syncthreads();
  const int t = blockIdx.x * 256 + tid;
  atomicAdd(&h[topi[2 * t]], 1);
  atomicAdd(&h[topi[2 * t + 1]], 1);
  __syncthreads();
  if (tid < NEXP) block_counts[blockIdx.x * NEXP + tid] = h[tid];
}

// ---------------- gather (scan fused; R5-proven) ----------------
__global__ void gather_kernel(const int* __restrict__ topi, const float* __restrict__ topw,
                              const int* __restrict__ block_counts, int* __restrict__ slot_tok,
                              float* __restrict__ slot_w, int* __restrict__ slot_of,
                              int* __restrict__ offsets, int* __restrict__ counts) {
  __shared__ int cur[NEXP];
  const int tid = threadIdx.x;
  if (tid < NEXP) {
    int off = 0;
    for (int f = 0; f < tid; f++)
      for (int b = 0; b < HIST_BLK; b++) off += block_counts[b * NEXP + f];
    int bb = off;
    for (int b = 0; b < (int)blockIdx.x; b++) bb += block_counts[b * NEXP + tid];
    cur[tid] = bb;
    if (blockIdx.x == 0) {
      offsets[tid] = off;
      int tot = 0;
      for (int b = 0; b < HIST_BLK; b++) tot += block_counts[b * NEXP + tid];
      counts[tid] = tot;
    }
  }
  __syncthreads();
  const int t = blockIdx.x * 256 + tid;
#pragma unroll
  for (int j = 0; j < 2; j++) {
    int e = topi[2 * t + j];
    int s = atomicAdd(&cur[e], 1);
    slot_tok[s] = t;
    slot_w[s] = topw[2 * t + j];
    slot_of[2 * t + j] = s;
  }
}

// ---------------- combine: out[t] += Y[slot0] + Y[slot1] ----------------
__global__ void combine_kernel(const bf16_t* __restrict__ Y, const int* __restrict__ slot_of,
                               float* __restrict__ out) {
  int i = blockIdx.x * blockDim.x + threadIdx.x;
  int t = i >> 7;
  int d = (i & 127) << 3;
  int s0 = slot_of[2 * t], s1 = slot_of[2 * t + 1];
  bf16x8 a = *reinterpret_cast<const bf16x8*>(Y + (size_t)s0 * DMODEL + d);
  bf16x8 b = *reinterpret_cast<const bf16x8*>(Y + (size_t)s1 * DMODEL + d);
  float* o = out + (size_t)t * DMODEL + d;
  float4 o0 = *reinterpret_cast<float4*>(o);
  float4 o1 = *reinterpret_cast<float4*>(o + 4);
  o0.x += (float)a[0] + (float)b[0]; o0.y += (float)a[1] + (float)b[1];
  o0.z += (float)a[2] + (float)b[2]; o0.w += (float)a[3] + (float)b[3];
  o1.x += (float)a[4] + (float)b[4]; o1.y += (float)a[5] + (float)b[5];
  o1.z += (float)a[6] + (float)b[6]; o1.w += (float)a[7] + (float)b[7];
  *reinterpret_cast<float4*>(o) = o0;
  *reinterpret_cast<float4*>(o + 4) = o1;
}

// ---------------- MFMA GEMM, 128x128 tile, BK=32 — R2-proven loop, UNTOUCHED ----------------
// MODE 0: S(bf16) = silu_pair(xb @ sgut interleaved)  [N=2048 cols -> 1024 via lane pairs]
// MODE 1: H(bf16) = silu(xb[slot_tok] @ w1t[e])
// MODE 2: Y(bf16) = slot_w * (H @ w2t[e])   (plain slot-major store)
// MODE 3: out(f32) = sig[m] * (S @ sdt)     (plain store; initializes d_out)
template <int MODE>
__global__ __launch_bounds__(256) void gemm_kernel(
    const bf16_t* __restrict__ A, const bf16_t* __restrict__ B, void* __restrict__ Cout,
    int N, const int* __restrict__ offsets, const int* __restrict__ counts,
    const int* __restrict__ slot_tok, const float* __restrict__ slot_w,
    const float* __restrict__ sig) {
  __shared__ bf16_t lds_a[BM * LDK];
  __shared__ bf16_t lds_b[BN * LDK];

  const int e = blockIdx.z;
  int m0, mEnd;
  const bf16_t* Bp = B;
  if (MODE == 1 || MODE == 2) {
    const int off = offsets[e], cnt = counts[e];
    m0 = off + (int)blockIdx.y * BM;
    mEnd = off + cnt;
    if (m0 >= mEnd) return;
    Bp += (size_t)e * FFN * DMODEL;
  } else {
    m0 = blockIdx.y * BM;
    mEnd = N_TOK;
  }
  const int n0 = blockIdx.x * BN;

  const int tid = threadIdx.x;
  const int lane = tid & 63;
  const int wave = tid >> 6;
  const int wm = (wave >> 1) * 64;
  const int wn = (wave & 1) * 64;
  const int qd = lane >> 4;
  const int lm = lane & 15;

  // staging: thread handles rows arow, arow+64 (per tile side), 16B chunk cc
  const int arow = tid >> 2;
  const int cc = tid & 3;
  const bf16_t* pa[2];
  const bf16_t* pb[2];
#pragma unroll
  for (int h = 0; h < 2; h++) {
    int s = m0 + arow + h * 64;
    int g;
    if (MODE == 1) g = slot_tok[(s < mEnd) ? s : (mEnd - 1)];
    else if (MODE == 2) g = (s < mEnd) ? s : (mEnd - 1);
    else g = s;
    pa[h] = A + (size_t)g * 1024 + cc * 8;  // K = 1024 all modes
    pb[h] = Bp + (size_t)(n0 + arow + h * 64) * 1024 + cc * 8;
  }

  f32x4 acc[4][4] = {};

  // R2-proven loop: plain global->reg->LDS each iter; compiler hoists/schedules loads itself.
  for (int k0 = 0; k0 < 1024; k0 += BK) {
    __syncthreads();
#pragma unroll
    for (int h = 0; h < 2; h++) {
      *reinterpret_cast<uint4*>(&lds_a[(arow + h * 64) * LDK + cc * 8]) =
          *reinterpret_cast<const uint4*>(pa[h] + k0);
      *reinterpret_cast<uint4*>(&lds_b[(arow + h * 64) * LDK + cc * 8]) =
          *reinterpret_cast<const uint4*>(pb[h] + k0);
    }
    __syncthreads();
    bf16x8 af[4], bfr[4];
#pragma unroll
    for (int i = 0; i < 4; i++)
      af[i] = *reinterpret_cast<const bf16x8*>(&lds_a[(wm + i * 16 + lm) * LDK + qd * 8]);
#pragma unroll
    for (int j = 0; j < 4; j++)
      bfr[j] = *reinterpret_cast<const bf16x8*>(&lds_b[(wn + j * 16 + lm) * LDK + qd * 8]);
#pragma unroll
    for (int i = 0; i < 4; i++)
#pragma unroll
      for (int j = 0; j < 4; j++)
        acc[i][j] = __builtin_amdgcn_mfma_f32_16x16x32_bf16(af[i], bfr[j], acc[i][j], 0, 0, 0);
  }

  // epilogue: C row = (lane>>4)*4 + reg, col = lane&15  [HW-verified]
#pragma unroll
  for (int i = 0; i < 4; i++) {
#pragma unroll
    for (int r = 0; r < 4; r++) {
      const int gm = m0 + wm + i * 16 + qd * 4 + r;
      const bool mOk = (MODE == 0 || MODE == 3) || (gm < mEnd);
      const float wgt = (MODE == 2 && mOk) ? slot_w[gm] : 0.f;
#pragma unroll
      for (int j = 0; j < 4; j++) {
        const int col = n0 + wn + j * 16 + lm;
        float v = acc[i][j][r];
        if (MODE == 0) {
          // cols interleaved: even = gate f, odd = up f (f = col>>1); pair via shfl_xor
          float u = __shfl_xor(v, 1, 64);
          if ((lane & 1) == 0) {
            float sv = v / (1.f + __expf(-v)) * u;
            ((bf16_t*)Cout)[(size_t)gm * FFN + (col >> 1)] = (bf16_t)sv;
          }
        } else if (MODE == 1) {
          if (mOk) ((bf16_t*)Cout)[(size_t)gm * FFN + col] = (bf16_t)(v / (1.f + __expf(-v)));
        } else if (MODE == 2) {
          if (mOk) ((bf16_t*)Cout)[(size_t)gm * DMODEL + col] = (bf16_t)(wgt * v);
        } else {
          ((float*)Cout)[(size_t)gm * DMODEL + col] = sig[gm] * v;
        }
      }
    }
  }
}

extern "C" void kernel_launch(void* const* d_in, const int* in_sizes, int n_in, void* d_out,
                              int out_size, void* d_ws, size_t ws_size, hipStream_t stream) {
  const float* x = (const float*)d_in[0];
  const float* rw = (const float*)d_in[1];
  const float* w1 = (const float*)d_in[2];
  const float* w2 = (const float*)d_in[3];
  const float* sgu = (const float*)d_in[4];
  const float* sdw = (const float*)d_in[5];
  const float* gw = (const float*)d_in[6];
  float* out = (float*)d_out;

  char* ws = (char*)d_ws;
  size_t off = 0;
  auto alloc = [&](size_t bytes) -> void* {
    void* p = ws + off;
    off += (bytes + 255) & ~(size_t)255;
    return p;
  };
  bf16_t* xb = (bf16_t*)alloc((size_t)N_TOK * DMODEL * 2);
  bf16_t* w1t = (bf16_t*)alloc((size_t)NEXP * DMODEL * FFN * 2);
  bf16_t* w2t = (bf16_t*)alloc((size_t)NEXP * DMODEL * FFN * 2);
  bf16_t* sgut = (bf16_t*)alloc((size_t)2 * FFN * DMODEL * 2);  // rows gate/up interleaved
  bf16_t* sdt = (bf16_t*)alloc((size_t)DMODEL * FFN * 2);
  bf16_t* S = (bf16_t*)alloc((size_t)N_TOK * FFN * 2);
  bf16_t* H = (bf16_t*)alloc((size_t)N_TOK * 2 * FFN * 2);    // slot-major
  bf16_t* Y = (bf16_t*)alloc((size_t)N_TOK * 2 * DMODEL * 2); // slot-major
  int* topi = (int*)alloc(N_TOK * 2 * 4);
  float* topw = (float*)alloc(N_TOK * 2 * 4);
  float* sig = (float*)alloc(N_TOK * 4);
  int* slot_tok = (int*)alloc(N_TOK * 2 * 4);
  float* slot_w = (float*)alloc(N_TOK * 2 * 4);
  int* slot_of = (int*)alloc(N_TOK * 2 * 4);
  int* block_counts = (int*)alloc(HIST_BLK * NEXP * 4);
  int* counts = (int*)alloc(NEXP * 4);
  int* offsets = (int*)alloc(NEXP * 4);

  // prep + routing (9 launches total)
  transpose_all_kernel<<<dim3(64, 32, 18), dim3(32, 8), 0, stream>>>(w1, w2, sgu, sdw, w1t, w2t,
                                                                     sgut, sdt);
  router_kernel<<<N_TOK, 64, 0, stream>>>(x, rw, gw, xb, topi, topw, sig);
  hist_kernel<<<HIST_BLK, 256, 0, stream>>>(topi, block_counts);
  gather_kernel<<<HIST_BLK, 256, 0, stream>>>(topi, topw, block_counts, slot_tok, slot_w,
                                              slot_of, offsets, counts);

  // shared up (silu fused into epilogue): S = silu(gate)*up
  gemm_kernel<0><<<dim3(2 * FFN / BN, N_TOK / BM, 1), 256, 0, stream>>>(
      xb, sgut, S, 2 * FFN, nullptr, nullptr, nullptr, nullptr, nullptr);
  // expert up: H = silu(xb[tok] @ w1t[e])
  gemm_kernel<1><<<dim3(FFN / BN, N_TOK / BM, NEXP), 256, 0, stream>>>(
      xb, w1t, H, FFN, offsets, counts, slot_tok, nullptr, nullptr);
  // expert down: Y = slot_w * (H @ w2t[e])
  gemm_kernel<2><<<dim3(DMODEL / BN, N_TOK / BM, NEXP), 256, 0, stream>>>(
      H, w2t, Y, DMODEL, offsets, counts, slot_tok, slot_w, nullptr);
  // shared down: out = sig * (S @ sdt)  (initializes d_out)
  gemm_kernel<3><<<dim3(DMODEL / BN, N_TOK / BM, 1), 256, 0, stream>>>(
      S, sdt, out, DMODEL, nullptr, nullptr, nullptr, nullptr, sig);
  // routed combine
  combine_kernel<<<N_TOK * DMODEL / 8 / 256, 256, 0, stream>>>(Y, slot_of, out);
}